// Round 4
// baseline (227.277 us; speedup 1.0000x reference)
//
#include <hip/hip_runtime.h>
#include <stdint.h>

#define N_CLASSES 100
#define ROWS_PER_WTILE 16
#define DW_PER_WTILE (ROWS_PER_WTILE * N_CLASSES)   /* 1600 dwords = 6.4 KB */
#define BLOCK 256
#define WAVES_PER_BLOCK (BLOCK / 64)
#define GRID 768          /* 3 blocks/CU (52 KB LDS each), 12 waves/CU streaming */
#define EPS 1e-7f

__device__ __forceinline__ void lds_dma16(void* lds, const void* g) {
    __builtin_amdgcn_global_load_lds(
        (const __attribute__((address_space(1))) uint32_t*)g,
        (__attribute__((address_space(3))) uint32_t*)lds, 16, 0, 0);
}
__device__ __forceinline__ void lds_dma4(void* lds, const void* g) {
    __builtin_amdgcn_global_load_lds(
        (const __attribute__((address_space(1))) uint32_t*)g,
        (__attribute__((address_space(3))) uint32_t*)lds, 4, 0, 0);
}

__global__ __launch_bounds__(BLOCK) void sens_kernel(
    const float* __restrict__ y_pred, const int* __restrict__ y_true,
    unsigned int* __restrict__ counters, float* __restrict__ out, int n_rows)
{
    __shared__ float s_rows[WAVES_PER_BLOCK][2][DW_PER_WTILE];  // 51.2 KB
    __shared__ unsigned int s_pc[N_CLASSES];
    __shared__ unsigned int s_tp[N_CLASSES];
    __shared__ int s_last;

    const int tid  = threadIdx.x;
    const int wave = tid >> 6;
    const int lane = tid & 63;

    for (int i = tid; i < N_CLASSES; i += BLOCK) { s_pc[i] = 0u; s_tp[i] = 0u; }
    __syncthreads();

    const long long n_wtiles = ((long long)n_rows + ROWS_PER_WTILE - 1) / ROWS_PER_WTILE;
    const long long total_dw = (long long)n_rows * N_CLASSES;
    const long long stride   = (long long)gridDim.x * WAVES_PER_BLOCK;

    // One wave-tile via LDS-DMA: 6x dwordx4 (full-exec) + 1x dword (full-exec)
    // = 7 uniform VMEM instructions -> literal vmcnt(7). Ragged tail tile takes
    // the 25x clamped-dword path; the counted wait only over-waits there (safe).
    auto issue = [&](long long tt, int b) {
        const long long base_dw = tt * (long long)DW_PER_WTILE;
        float* dst = s_rows[wave][b];
        const float* gp = y_pred + base_dw;
        if (base_dw + DW_PER_WTILE <= total_dw) {
            #pragma unroll
            for (int k = 0; k < 6; ++k) {
                const int i = (k * 64 + lane) * 4;   // dword index, 16B granular
                lds_dma16(dst + i, gp + i);
            }
            const int j = 6 * 64 * 4 + lane;         // final 64 dwords
            lds_dma4(dst + j, gp + j);
        } else {
            #pragma unroll
            for (int k = 0; k < 25; ++k) {
                const int i = k * 64 + lane;
                long long gi = base_dw + i;
                if (gi >= total_dw) gi = total_dw - 1;
                lds_dma4(dst + i, y_pred + gi);
            }
        }
    };

    auto compute = [&](long long tt, int b, int tv) {
        const int r = lane >> 2;                     // row in wave-tile
        const int q = lane & 3;                      // quarter of row
        const long long grow = tt * ROWS_PER_WTILE + r;
        if (grow < (long long)n_rows) {
            const float* rowp = &s_rows[wave][b][r * N_CLASSES + q * 25];
            float best = rowp[0];
            int bidx = q * 25;
            #pragma unroll
            for (int i2 = 1; i2 < 25; ++i2) {
                float v = rowp[i2];
                if (v > best) { best = v; bidx = q * 25 + i2; }  // strict >: first max
            }
            #pragma unroll
            for (int m = 1; m <= 2; m <<= 1) {
                float ov = __shfl_xor(best, m, 64);
                int   oi = __shfl_xor(bidx, m, 64);
                if (ov > best || (ov == best && oi < bidx)) { best = ov; bidx = oi; }
            }
            if (q == 0) {
                atomicAdd(&s_pc[bidx], 1u);
                if (tv == bidx) atomicAdd(&s_tp[bidx], 1u);
            }
        }
    };

    long long t = (long long)blockIdx.x * WAVES_PER_BLOCK + wave;
    int cur = 0;
    if (t < n_wtiles) {
        issue(t, 0);                                  // prologue
        long long nxt = t + stride;
        // Main loop: straight-line body (no branch around issue) so the
        // compiler's waitcnt tracking matches our counted vmcnt(7) exactly.
        while (nxt < n_wtiles) {
            int tv;
            const int* typ = y_true + t * ROWS_PER_WTILE + (lane >> 2);
            asm volatile("global_load_dword %0, %1, off"
                         : "=v"(tv) : "v"(typ) : "memory");
            issue(nxt, cur ^ 1);
            // drain: current tile's 7 DMA + the tv load; keep next tile's 7 in flight
            asm volatile("s_waitcnt vmcnt(7)" ::: "memory");
            __builtin_amdgcn_sched_barrier(0);        // rule #18: no hoisting past wait
            compute(t, cur, tv);
            cur ^= 1;
            t = nxt;
            nxt += stride;
        }
        // Epilogue: last tile for this wave-stream (possibly ragged)
        {
            const long long grow = t * ROWS_PER_WTILE + (lane >> 2);
            int tv = -1;
            if (grow < (long long)n_rows) tv = y_true[grow];
            asm volatile("s_waitcnt vmcnt(0)" ::: "memory");
            __builtin_amdgcn_sched_barrier(0);
            compute(t, cur, tv);
        }
    }

    // ---- block flush ----
    __syncthreads();
    for (int i = tid; i < N_CLASSES; i += BLOCK) {
        unsigned int pc = s_pc[i], tp = s_tp[i];
        if (pc) atomicAdd(&counters[i], pc);
        if (tp) atomicAdd(&counters[N_CLASSES + i], tp);
    }
    __threadfence();                                  // release our counter adds
    __syncthreads();
    if (tid == 0) {
        unsigned int old = atomicAdd(&counters[2 * N_CLASSES], 1u);
        s_last = (old == (unsigned int)(gridDim.x - 1)) ? 1 : 0;
    }
    __syncthreads();

    // ---- last block finalizes (replaces separate kernel dispatch) ----
    if (s_last && tid < 64) {
        __threadfence();                              // acquire all blocks' adds
        float acc = 0.f;
        for (int c = tid; c < N_CLASSES; c += 64) {
            unsigned int pc = __hip_atomic_load(&counters[c],
                                __ATOMIC_RELAXED, __HIP_MEMORY_SCOPE_AGENT);
            unsigned int tp = __hip_atomic_load(&counters[N_CLASSES + c],
                                __ATOMIC_RELAXED, __HIP_MEMORY_SCOPE_AGENT);
            acc += (float)tp / ((float)pc + EPS);
        }
        #pragma unroll
        for (int m = 32; m >= 1; m >>= 1) acc += __shfl_xor(acc, m, 64);
        if (tid == 0) out[0] = acc / (float)N_CLASSES;
    }
}

extern "C" void kernel_launch(void* const* d_in, const int* in_sizes, int n_in,
                              void* d_out, int out_size, void* d_ws, size_t ws_size,
                              hipStream_t stream)
{
    const float* y_pred = (const float*)d_in[0];
    const int*   y_true = (const int*)d_in[1];
    float* out = (float*)d_out;
    const int n_rows = in_sizes[1];  // 2,000,000

    unsigned int* counters = (unsigned int*)d_ws;  // [pc:100][tp:100][done:1]
    hipMemsetAsync(counters, 0, (2 * N_CLASSES + 1) * sizeof(unsigned int), stream);

    sens_kernel<<<GRID, BLOCK, 0, stream>>>(y_pred, y_true, counters, out, n_rows);
}

// Round 5
// 223.066 us; speedup vs baseline: 1.0189x; 1.0189x over previous
//
#include <hip/hip_runtime.h>
#include <stdint.h>

#define N_CLASSES 100
#define ROWS_PER_WTILE 16
#define DW_PER_WTILE (ROWS_PER_WTILE * N_CLASSES)   /* 1600 dwords = 6.4 KB */
#define LOADS_PER_LANE (DW_PER_WTILE / 64)          /* 25 -> vmcnt(25) */
#define BLOCK 256
#define WAVES_PER_BLOCK (BLOCK / 64)
#define GRID 768          /* 3 blocks/CU (52 KB LDS), 12 waves/CU streaming */
#define EPS 1e-7f

__device__ __forceinline__ void lds_dma4(void* lds, const void* g) {
    __builtin_amdgcn_global_load_lds(
        (const __attribute__((address_space(1))) uint32_t*)g,
        (__attribute__((address_space(3))) uint32_t*)lds, 4, 0, 0);
}

__global__ __launch_bounds__(BLOCK) void sens_kernel(
    const float* __restrict__ y_pred, const int* __restrict__ y_true,
    unsigned int* __restrict__ counters, float* __restrict__ out, int n_rows)
{
    // Wave-private double buffers: no s_barrier in the main loop. (R3 structure.)
    __shared__ float s_rows[WAVES_PER_BLOCK][2][DW_PER_WTILE];  // 4*2*6.4KB = 51.2KB
    __shared__ unsigned int s_pc[N_CLASSES];
    __shared__ unsigned int s_tp[N_CLASSES];
    __shared__ int s_last;

    const int tid  = threadIdx.x;
    const int wave = tid >> 6;
    const int lane = tid & 63;

    for (int i = tid; i < N_CLASSES; i += BLOCK) { s_pc[i] = 0u; s_tp[i] = 0u; }
    __syncthreads();   // hist zero-init visible before any atomics

    const long long n_wtiles = ((long long)n_rows + ROWS_PER_WTILE - 1) / ROWS_PER_WTILE;
    const long long total_dw = (long long)n_rows * N_CLASSES;
    const long long stride   = (long long)gridDim.x * WAVES_PER_BLOCK;

    // Issue one wave-tile via DMA. LDS dst = wave-uniform base + lane*4 (contract).
    auto issue = [&](long long t, int b) {
        const long long base = t * (long long)DW_PER_WTILE;
        float* dst = s_rows[wave][b];
        const float* gp = y_pred + base;
        if (base + DW_PER_WTILE <= total_dw) {      // full tile: no per-load clamp
            #pragma unroll
            for (int k = 0; k < LOADS_PER_LANE; ++k) {
                const int i = k * 64 + lane;
                lds_dma4(dst + i, gp + i);
            }
        } else {
            #pragma unroll
            for (int k = 0; k < LOADS_PER_LANE; ++k) {
                const int i = k * 64 + lane;
                long long gi = base + i;
                if (gi >= total_dw) gi = total_dw - 1;
                lds_dma4(dst + i, y_pred + gi);
            }
        }
    };

    long long t = (long long)blockIdx.x * WAVES_PER_BLOCK + wave;
    int cur = 0;
    if (t < n_wtiles) issue(t, 0);   // prologue: first tile in flight

    for (; t < n_wtiles; t += stride) {
        const int r = lane >> 2;     // row in wave-tile, 0..15
        const int q = lane & 3;      // quarter of row
        const long long grow = t * ROWS_PER_WTILE + r;

        // y_true prefetch BEFORE next-tile issue -> its auto-waitcnt is vmcnt(25).
        int tv = -1;
        if (grow < (long long)n_rows) tv = y_true[grow];

        const long long nxt = t + stride;
        if (nxt < n_wtiles) {
            issue(nxt, cur ^ 1);
            asm volatile("s_waitcnt vmcnt(25)" ::: "memory");  // current tile + tv landed
        } else {
            asm volatile("s_waitcnt vmcnt(0)" ::: "memory");   // epilogue drain
        }

        if (grow < (long long)n_rows) {
            const float* rowp = &s_rows[wave][cur][r * N_CLASSES + q * 25];
            float best = rowp[0];
            int bidx = q * 25;
            #pragma unroll
            for (int i2 = 1; i2 < 25; ++i2) {
                float v = rowp[i2];
                if (v > best) { best = v; bidx = q * 25 + i2; }  // strict >: first max
            }
            #pragma unroll
            for (int m = 1; m <= 2; m <<= 1) {
                float ov = __shfl_xor(best, m, 64);
                int   oi = __shfl_xor(bidx, m, 64);
                if (ov > best || (ov == best && oi < bidx)) { best = ov; bidx = oi; }
            }
            if (q == 0) {
                atomicAdd(&s_pc[bidx], 1u);
                if (tv == bidx) atomicAdd(&s_tp[bidx], 1u);
            }
        }
        cur ^= 1;
    }

    // ---- block flush (unchanged from R3) ----
    __syncthreads();   // all waves' LDS hist atomics done
    for (int i = tid; i < N_CLASSES; i += BLOCK) {
        unsigned int pc = s_pc[i], tp = s_tp[i];
        if (pc) atomicAdd(&counters[i], pc);
        if (tp) atomicAdd(&counters[N_CLASSES + i], tp);
    }

    // ---- ONE change vs R3: last-block-done finalize replaces the 3rd dispatch ----
    __threadfence();                                  // release our counter adds
    __syncthreads();
    if (tid == 0) {
        unsigned int old = atomicAdd(&counters[2 * N_CLASSES], 1u);
        s_last = (old == (unsigned int)(gridDim.x - 1)) ? 1 : 0;
    }
    __syncthreads();

    if (s_last && tid < 64) {
        __threadfence();                              // acquire all blocks' adds
        float acc = 0.f;
        for (int c = tid; c < N_CLASSES; c += 64) {
            unsigned int pc = __hip_atomic_load(&counters[c],
                                __ATOMIC_RELAXED, __HIP_MEMORY_SCOPE_AGENT);
            unsigned int tp = __hip_atomic_load(&counters[N_CLASSES + c],
                                __ATOMIC_RELAXED, __HIP_MEMORY_SCOPE_AGENT);
            acc += (float)tp / ((float)pc + EPS);
        }
        #pragma unroll
        for (int m = 32; m >= 1; m >>= 1) acc += __shfl_xor(acc, m, 64);
        if (tid == 0) out[0] = acc / (float)N_CLASSES;
    }
}

extern "C" void kernel_launch(void* const* d_in, const int* in_sizes, int n_in,
                              void* d_out, int out_size, void* d_ws, size_t ws_size,
                              hipStream_t stream)
{
    const float* y_pred = (const float*)d_in[0];
    const int*   y_true = (const int*)d_in[1];
    float* out = (float*)d_out;
    const int n_rows = in_sizes[1];  // 2,000,000

    unsigned int* counters = (unsigned int*)d_ws;  // [pc:100][tp:100][done:1]
    hipMemsetAsync(counters, 0, (2 * N_CLASSES + 1) * sizeof(unsigned int), stream);

    sens_kernel<<<GRID, BLOCK, 0, stream>>>(y_pred, y_true, counters, out, n_rows);
}

// Round 6
// 148.208 us; speedup vs baseline: 1.5335x; 1.5051x over previous
//
#include <hip/hip_runtime.h>
#include <stdint.h>

#define N_CLASSES 100
#define ROWS_PER_WTILE 16
#define DW_PER_WTILE (ROWS_PER_WTILE * N_CLASSES)   /* 1600 dwords = 6.4 KB */
#define LOADS_PER_LANE (DW_PER_WTILE / 64)          /* 25 -> vmcnt(25) */
#define BLOCK 256
#define WAVES_PER_BLOCK (BLOCK / 64)
#define EPS 1e-7f

__device__ __forceinline__ void lds_dma4(void* lds, const void* g) {
    __builtin_amdgcn_global_load_lds(
        (const __attribute__((address_space(1))) uint32_t*)g,
        (__attribute__((address_space(3))) uint32_t*)lds, 4, 0, 0);
}

__global__ __launch_bounds__(BLOCK) void sens_count_kernel(
    const float* __restrict__ y_pred, const int* __restrict__ y_true,
    unsigned int* __restrict__ counters, int n_rows)
{
    // Wave-private double buffers: no s_barrier in the main loop.
    __shared__ float s_rows[WAVES_PER_BLOCK][2][DW_PER_WTILE];  // 4*2*6.4KB = 51.2KB
    __shared__ unsigned int s_pc[N_CLASSES];
    __shared__ unsigned int s_tp[N_CLASSES];

    const int tid  = threadIdx.x;
    const int wave = tid >> 6;
    const int lane = tid & 63;

    for (int i = tid; i < N_CLASSES; i += BLOCK) { s_pc[i] = 0u; s_tp[i] = 0u; }
    __syncthreads();   // hist zero-init visible before any atomics

    const long long n_wtiles = ((long long)n_rows + ROWS_PER_WTILE - 1) / ROWS_PER_WTILE;
    const long long total_dw = (long long)n_rows * N_CLASSES;
    const long long stride   = (long long)gridDim.x * WAVES_PER_BLOCK;

    // Issue one wave-tile via DMA. LDS dst = wave-uniform base + lane*4 (contract).
    auto issue = [&](long long t, int b) {
        const long long base = t * (long long)DW_PER_WTILE;
        float* dst = s_rows[wave][b];
        const float* gp = y_pred + base;
        if (base + DW_PER_WTILE <= total_dw) {      // full tile: no per-load clamp
            #pragma unroll
            for (int k = 0; k < LOADS_PER_LANE; ++k) {
                const int i = k * 64 + lane;
                lds_dma4(dst + i, gp + i);
            }
        } else {
            #pragma unroll
            for (int k = 0; k < LOADS_PER_LANE; ++k) {
                const int i = k * 64 + lane;
                long long gi = base + i;
                if (gi >= total_dw) gi = total_dw - 1;
                lds_dma4(dst + i, y_pred + gi);
            }
        }
    };

    long long t = (long long)blockIdx.x * WAVES_PER_BLOCK + wave;
    int cur = 0;
    if (t < n_wtiles) issue(t, 0);   // prologue: first tile in flight

    for (; t < n_wtiles; t += stride) {
        const int r = lane >> 2;     // row in wave-tile, 0..15
        const int q = lane & 3;      // quarter of row
        const long long grow = t * ROWS_PER_WTILE + r;

        // y_true prefetch BEFORE next-tile issue -> its auto-waitcnt is vmcnt(25).
        int tv = -1;
        if (grow < (long long)n_rows) tv = y_true[grow];

        const long long nxt = t + stride;
        if (nxt < n_wtiles) {
            issue(nxt, cur ^ 1);
            asm volatile("s_waitcnt vmcnt(25)" ::: "memory");  // current tile + tv landed
        } else {
            asm volatile("s_waitcnt vmcnt(0)" ::: "memory");   // epilogue drain
        }

        if (grow < (long long)n_rows) {
            const float* rowp = &s_rows[wave][cur][r * N_CLASSES + q * 25];
            float best = rowp[0];
            int bidx = q * 25;
            #pragma unroll
            for (int i2 = 1; i2 < 25; ++i2) {
                float v = rowp[i2];
                if (v > best) { best = v; bidx = q * 25 + i2; }  // strict >: first max
            }
            #pragma unroll
            for (int m = 1; m <= 2; m <<= 1) {
                float ov = __shfl_xor(best, m, 64);
                int   oi = __shfl_xor(bidx, m, 64);
                if (ov > best || (ov == best && oi < bidx)) { best = ov; bidx = oi; }
            }
            if (q == 0) {
                atomicAdd(&s_pc[bidx], 1u);
                if (tv == bidx) atomicAdd(&s_tp[bidx], 1u);
            }
        }
        cur ^= 1;
    }

    __syncthreads();   // all waves' LDS hist atomics done
    for (int i = tid; i < N_CLASSES; i += BLOCK) {
        unsigned int pc = s_pc[i], tp = s_tp[i];
        if (pc) atomicAdd(&counters[i], pc);
        if (tp) atomicAdd(&counters[N_CLASSES + i], tp);
    }
}

__global__ void sens_final_kernel(const unsigned int* __restrict__ counters,
                                  float* __restrict__ out)
{
    const int lane = threadIdx.x;  // one wave
    float acc = 0.f;
    for (int c = lane; c < N_CLASSES; c += 64) {
        float pc = (float)counters[c];
        float tp = (float)counters[N_CLASSES + c];
        acc += tp / (pc + EPS);
    }
    #pragma unroll
    for (int m = 32; m >= 1; m >>= 1) acc += __shfl_xor(acc, m, 64);
    if (lane == 0) out[0] = acc / (float)N_CLASSES;
}

extern "C" void kernel_launch(void* const* d_in, const int* in_sizes, int n_in,
                              void* d_out, int out_size, void* d_ws, size_t ws_size,
                              hipStream_t stream)
{
    const float* y_pred = (const float*)d_in[0];
    const int*   y_true = (const int*)d_in[1];
    float* out = (float*)d_out;
    const int n_rows = in_sizes[1];  // 2,000,000

    unsigned int* counters = (unsigned int*)d_ws;  // [pc:100][tp:100]
    hipMemsetAsync(counters, 0, 2 * N_CLASSES * sizeof(unsigned int), stream);

    const int grid = 768;  // 3 blocks/CU (52KB LDS each), 15 waves/CU streaming
    sens_count_kernel<<<grid, BLOCK, 0, stream>>>(y_pred, y_true, counters, n_rows);
    sens_final_kernel<<<1, 64, 0, stream>>>(counters, out);
}